// Round 4
// baseline (3513.419 us; speedup 1.0000x reference)
//
#include <hip/hip_runtime.h>
#include <hip/hip_bf16.h>
#include <hip/hip_fp16.h>

#define T_ 1024
#define B_ 32
#define H_ 256
#define G3 768   // 3*H

typedef _Float16 half2_t __attribute__((ext_vector_type(2)));

__device__ __forceinline__ float sigmoidf_(float x) { return 1.f / (1.f + __expf(-x)); }
__device__ __forceinline__ float tanhf_(float x) {
    float e = __expf(2.f * x);
    return (e - 1.f) / (e + 1.f);
}

// LDS-only barrier: does NOT drain vmcnt, so global prefetch loads / output
// stores stay in flight across it.
__device__ __forceinline__ void sync_lds() {
    asm volatile("s_waitcnt lgkmcnt(0)" ::: "memory");
    asm volatile("s_barrier" ::: "memory");
}

__device__ __forceinline__ float fdot2_(unsigned int w, unsigned int h, float acc) {
#if __has_builtin(__builtin_amdgcn_fdot2)
    return __builtin_amdgcn_fdot2(__builtin_bit_cast(half2_t, w),
                                  __builtin_bit_cast(half2_t, h), acc, false);
#else
    half2_t a = __builtin_bit_cast(half2_t, w);
    half2_t b = __builtin_bit_cast(half2_t, h);
    return acc + (float)a[0] * (float)b[0] + (float)a[1] * (float)b[1];
#endif
}

__device__ __forceinline__ unsigned int pack_f16rn(float x, float y) {
    unsigned short ux = __half_as_ushort(__float2half_rn(x));
    unsigned short uy = __half_as_ushort(__float2half_rn(y));
    return (unsigned int)ux | ((unsigned int)uy << 16);
}

// C[M,N] = A[M,K] @ W[N,K]^T + bias[N]
template <typename CT>
__global__ __launch_bounds__(256) void gemm_bias_nt(
    const float* __restrict__ A, const float* __restrict__ W,
    const float* __restrict__ bias, CT* __restrict__ C,
    int M, int N, int K)
{
    __shared__ float As[16][68];
    __shared__ float Ws[16][68];
    const int tid = threadIdx.x;
    const int bm = blockIdx.y * 64;
    const int bn = blockIdx.x * 64;
    const int lr = tid & 63;
    const int lc = tid >> 6;
    const int tx = tid & 15;
    const int ty = tid >> 4;

    const float* Ap = A + (size_t)(bm + lr) * K + lc * 4;
    const float* Wp = W + (size_t)(bn + lr) * K + lc * 4;

    float acc[4][4];
#pragma unroll
    for (int i = 0; i < 4; ++i)
#pragma unroll
        for (int j = 0; j < 4; ++j) acc[i][j] = 0.f;

    for (int k0 = 0; k0 < K; k0 += 16) {
        float4 av = *(const float4*)(Ap + k0);
        float4 wv = *(const float4*)(Wp + k0);
        __syncthreads();
        As[lc * 4 + 0][lr] = av.x; As[lc * 4 + 1][lr] = av.y;
        As[lc * 4 + 2][lr] = av.z; As[lc * 4 + 3][lr] = av.w;
        Ws[lc * 4 + 0][lr] = wv.x; Ws[lc * 4 + 1][lr] = wv.y;
        Ws[lc * 4 + 2][lr] = wv.z; Ws[lc * 4 + 3][lr] = wv.w;
        __syncthreads();
#pragma unroll
        for (int kk = 0; kk < 16; ++kk) {
            float4 a4 = *(const float4*)&As[kk][ty * 4];
            float4 w4 = *(const float4*)&Ws[kk][tx * 4];
            float am[4] = {a4.x, a4.y, a4.z, a4.w};
            float wn[4] = {w4.x, w4.y, w4.z, w4.w};
#pragma unroll
            for (int i = 0; i < 4; ++i)
#pragma unroll
                for (int j = 0; j < 4; ++j) acc[i][j] += am[i] * wn[j];
        }
    }

#pragma unroll
    for (int i = 0; i < 4; ++i) {
        size_t cbase = (size_t)(bm + ty * 4 + i) * N + bn + tx * 4;
#pragma unroll
        for (int j = 0; j < 4; ++j) {
            float v = acc[i][j] + bias[bn + tx * 4 + j];
            C[cbase + j] = (CT)v;
        }
    }
}

// One WG per (batch, direction), 512 threads = (j 0..255, kh 0..1).
// W_hh register-resident as packed f16x2 (192 VGPRs/thread). Transient
// pressure is capped with sched_barrier(0) windows so the allocator keeps the
// weights in ARCH VGPRs (not AGPRs -> no v_accvgpr_read per fdot2).
template <typename PT>
__global__ __launch_bounds__(512, 2) void gru_scan_reg(
    const PT* __restrict__ Pf, const PT* __restrict__ Pb,
    const float* __restrict__ Wf, const float* __restrict__ Wb,
    const float* __restrict__ bhf, const float* __restrict__ bhb,
    const int* __restrict__ lengths,
    float* __restrict__ out,   // (T,B,512)
    float* __restrict__ hn,    // [dir][b][j]
    int do_mask)
{
    const int b = blockIdx.x >> 1;
    const int dir = blockIdx.x & 1;
    const PT* P = dir ? Pb : Pf;
    const float* W = dir ? Wb : Wf;
    const float* bh = dir ? bhb : bhf;
    const int len = lengths[b];

    __shared__ unsigned short h16s[H_];   // h as f16 for the matvec
    __shared__ float part[3][H_];         // kh=1 partials only

    const int tid = threadIdx.x;
    const int j = tid & 255;
    const int kh = tid >> 8;

    // ---- load W_hh into registers; chunked (<=6 float4 temps in flight) ----
    unsigned int wr[64], wz[64], wn[64];
    {
        const float4* r0 = (const float4*)(W + (size_t)j * H_ + kh * 128);
        const float4* r1 = (const float4*)(W + (size_t)(j + 256) * H_ + kh * 128);
        const float4* r2 = (const float4*)(W + (size_t)(j + 512) * H_ + kh * 128);
#pragma unroll
        for (int q = 0; q < 32; ++q) {
            float4 a = r0[q]; wr[2 * q] = pack_f16rn(a.x, a.y); wr[2 * q + 1] = pack_f16rn(a.z, a.w);
            float4 c = r1[q]; wz[2 * q] = pack_f16rn(c.x, c.y); wz[2 * q + 1] = pack_f16rn(c.z, c.w);
            float4 d = r2[q]; wn[2 * q] = pack_f16rn(d.x, d.y); wn[2 * q + 1] = pack_f16rn(d.z, d.w);
            if ((q & 1) == 1) __builtin_amdgcn_sched_barrier(0);
        }
    }

    float bh0 = 0.f, bh1 = 0.f, bh2 = 0.f;
    if (tid < H_) { bh0 = bh[j]; bh1 = bh[j + 256]; bh2 = bh[j + 512]; }

    float hreg = 0.f;
    if (tid < H_) h16s[tid] = 0;

    float* outp = out + (size_t)b * 512 + dir * 256;
    float* hnp = hn + (size_t)dir * (B_ * H_) + (size_t)b * H_;

    int crow = dir ? ((len - 1) & (T_ - 1)) : 0;   // row of current step
    int prow = dir ? ((len - 2) & (T_ - 1)) : 1;   // row of next step (prefetch)
    const int rstep = dir ? -1 : 1;
    const PT* Pbase = P + (size_t)b * G3 + j;

    // prologue: P for step 0
    float cir = 0.f, ciz = 0.f, cin = 0.f;
    if (tid < H_) {
        const PT* pp = Pbase + (size_t)crow * (B_ * G3);
        cir = (float)pp[0]; ciz = (float)pp[256]; cin = (float)pp[512];
    }
    sync_lds();

#pragma unroll 1
    for (int s = 0; s < T_; ++s) {
        // prefetch next step's input projections (stays in flight across barriers)
        float nir = 0.f, niz = 0.f, nin = 0.f;
        if (s + 1 < T_ && tid < H_) {
            const PT* pp = Pbase + (size_t)prow * (B_ * G3);
            nir = (float)pp[0]; niz = (float)pp[256]; nin = (float)pp[512];
        }

        // ---- matvec: 2-deep pipelined h-tile reads, weights in VGPRs ----
        float ar0 = 0.f, ar1 = 0.f, az0 = 0.f, az1 = 0.f, an0 = 0.f, an1 = 0.f;
        const uint4* hv = ((const uint4*)h16s) + kh * 16;
        uint4 c0 = hv[0], c1 = hv[1];
        uint4 n0 = hv[2], n1 = hv[3];
#pragma unroll
        for (int m = 0; m < 8; ++m) {
            uint4 f0 = {}, f1 = {};
            if (m < 6) { f0 = hv[2 * m + 4]; f1 = hv[2 * m + 5]; }
            ar0 = fdot2_(wr[8 * m + 0], c0.x, ar0);
            az0 = fdot2_(wz[8 * m + 0], c0.x, az0);
            an0 = fdot2_(wn[8 * m + 0], c0.x, an0);
            ar1 = fdot2_(wr[8 * m + 1], c0.y, ar1);
            az1 = fdot2_(wz[8 * m + 1], c0.y, az1);
            an1 = fdot2_(wn[8 * m + 1], c0.y, an1);
            ar0 = fdot2_(wr[8 * m + 2], c0.z, ar0);
            az0 = fdot2_(wz[8 * m + 2], c0.z, az0);
            an0 = fdot2_(wn[8 * m + 2], c0.z, an0);
            ar1 = fdot2_(wr[8 * m + 3], c0.w, ar1);
            az1 = fdot2_(wz[8 * m + 3], c0.w, az1);
            an1 = fdot2_(wn[8 * m + 3], c0.w, an1);
            ar0 = fdot2_(wr[8 * m + 4], c1.x, ar0);
            az0 = fdot2_(wz[8 * m + 4], c1.x, az0);
            an0 = fdot2_(wn[8 * m + 4], c1.x, an0);
            ar1 = fdot2_(wr[8 * m + 5], c1.y, ar1);
            az1 = fdot2_(wz[8 * m + 5], c1.y, az1);
            an1 = fdot2_(wn[8 * m + 5], c1.y, an1);
            ar0 = fdot2_(wr[8 * m + 6], c1.z, ar0);
            az0 = fdot2_(wz[8 * m + 6], c1.z, az0);
            an0 = fdot2_(wn[8 * m + 6], c1.z, an0);
            ar1 = fdot2_(wr[8 * m + 7], c1.w, ar1);
            az1 = fdot2_(wz[8 * m + 7], c1.w, az1);
            an1 = fdot2_(wn[8 * m + 7], c1.w, an1);
            __builtin_amdgcn_sched_barrier(0);
            c0 = n0; c1 = n1; n0 = f0; n1 = f1;
        }
        const float ar = ar0 + ar1;
        const float az = az0 + az1;
        const float an = an0 + an1;
        if (kh) {                         // wave-uniform (waves 4-7)
            part[0][j] = ar;
            part[1][j] = az;
            part[2][j] = an;
        }
        sync_lds();

        if (tid < H_) {                   // waves 0-3: epilogue
            float gr = ar + part[0][j] + bh0;
            float gz = az + part[1][j] + bh1;
            float gn = an + part[2][j] + bh2;
            float r = sigmoidf_(cir + gr);
            float z = sigmoidf_(ciz + gz);
            float nn = tanhf_(cin + r * gn);
            float hnew = (1.f - z) * nn + z * hreg;
            hreg = hnew;
            h16s[j] = __half_as_ushort(__float2half_rn(hnew));
            float ov = (do_mask && crow >= len) ? 0.f : hnew;
            outp[(size_t)crow * (B_ * 512) + j] = ov;
            if (s == len - 1) hnp[j] = hnew;
        }
        sync_lds();

        cir = nir; ciz = niz; cin = nin;
        crow = (crow + rstep) & (T_ - 1);
        prow = (prow + rstep) & (T_ - 1);
    }
}

extern "C" void kernel_launch(void* const* d_in, const int* in_sizes, int n_in,
                              void* d_out, int out_size, void* d_ws, size_t ws_size,
                              hipStream_t stream)
{
    const float* x        = (const float*)d_in[0];
    const float* w_ih_l0f = (const float*)d_in[1];
    const float* w_hh_l0f = (const float*)d_in[2];
    const float* b_ih_l0f = (const float*)d_in[3];
    const float* b_hh_l0f = (const float*)d_in[4];
    const float* w_ih_l0b = (const float*)d_in[5];
    const float* w_hh_l0b = (const float*)d_in[6];
    const float* b_ih_l0b = (const float*)d_in[7];
    const float* b_hh_l0b = (const float*)d_in[8];
    const float* w_ih_l1f = (const float*)d_in[9];
    const float* w_hh_l1f = (const float*)d_in[10];
    const float* b_ih_l1f = (const float*)d_in[11];
    const float* b_hh_l1f = (const float*)d_in[12];
    const float* w_ih_l1b = (const float*)d_in[13];
    const float* w_hh_l1b = (const float*)d_in[14];
    const float* b_ih_l1b = (const float*)d_in[15];
    const float* b_hh_l1b = (const float*)d_in[16];
    const int*   lengths  = (const int*)d_in[17];

    float* out = (float*)d_out;
    const size_t OUT_OFF = (size_t)T_ * B_ * 512;
    float* hn0 = out + OUT_OFF;
    float* hn1 = hn0 + 2 * B_ * H_;

    const size_t PE = (size_t)T_ * B_ * G3;
    const int M = T_ * B_;
    dim3 gg(G3 / 64, M / 64);

    if (ws_size >= 2 * PE * sizeof(float)) {
        float* P0 = (float*)d_ws;
        float* P1 = P0 + PE;
        gemm_bias_nt<float><<<gg, 256, 0, stream>>>(x, w_ih_l0f, b_ih_l0f, P0, M, G3, 256);
        gemm_bias_nt<float><<<gg, 256, 0, stream>>>(x, w_ih_l0b, b_ih_l0b, P1, M, G3, 256);
        gru_scan_reg<float><<<64, 512, 0, stream>>>(P0, P1, w_hh_l0f, w_hh_l0b,
                                                    b_hh_l0f, b_hh_l0b, lengths, out, hn0, 0);
        gemm_bias_nt<float><<<gg, 256, 0, stream>>>(out, w_ih_l1f, b_ih_l1f, P0, M, G3, 512);
        gemm_bias_nt<float><<<gg, 256, 0, stream>>>(out, w_ih_l1b, b_ih_l1b, P1, M, G3, 512);
        gru_scan_reg<float><<<64, 512, 0, stream>>>(P0, P1, w_hh_l1f, w_hh_l1b,
                                                    b_hh_l1f, b_hh_l1b, lengths, out, hn1, 1);
    } else if (ws_size >= 2 * PE * sizeof(__hip_bfloat16)) {
        __hip_bfloat16* P0 = (__hip_bfloat16*)d_ws;
        __hip_bfloat16* P1 = P0 + PE;
        gemm_bias_nt<__hip_bfloat16><<<gg, 256, 0, stream>>>(x, w_ih_l0f, b_ih_l0f, P0, M, G3, 256);
        gemm_bias_nt<__hip_bfloat16><<<gg, 256, 0, stream>>>(x, w_ih_l0b, b_ih_l0b, P1, M, G3, 256);
        gru_scan_reg<__hip_bfloat16><<<64, 512, 0, stream>>>(P0, P1, w_hh_l0f, w_hh_l0b,
                                                             b_hh_l0f, b_hh_l0b, lengths, out, hn0, 0);
        gemm_bias_nt<__hip_bfloat16><<<gg, 256, 0, stream>>>(out, w_ih_l1f, b_ih_l1f, P0, M, G3, 512);
        gemm_bias_nt<__hip_bfloat16><<<gg, 256, 0, stream>>>(out, w_ih_l1b, b_ih_l1b, P1, M, G3, 512);
        gru_scan_reg<__hip_bfloat16><<<64, 512, 0, stream>>>(P0, P1, w_hh_l1f, w_hh_l1b,
                                                             b_hh_l1f, b_hh_l1b, lengths, out, hn1, 1);
    }
}